// Round 4
// baseline (281.223 us; speedup 1.0000x reference)
//
#include <hip/hip_runtime.h>

// B=16, C=64, H=W=192, K=3 (fixed).
// Kernel 1: ker[b,c,i,j] from the tiny MLP (16 blocks, writes 9216 floats to ws).
// Kernel 2 (v7): depthwise 3x3, persistent per-plane blocks + double-buffered
// LDS staging in the SAFE m97 2-phase form (no inline-asm waits, no raw
// s_barrier -- v6's counted-vmcnt schedule raced and used unverified 12B
// global_load_lds widths):
//   - Grid = 1024 blocks (one per (b,c) plane) = exactly 4 blocks/CU, no tail.
//   - Plane split into 8 tiles of 24 output rows. Per tile, the NEXT 26-row
//     window (20480 B = 5 x 16B global_load_lds per thread, tail clamped) is
//     issued into the other LDS buffer BEFORE computing the current tile;
//     the end-of-iteration __syncthreads() (compiler emits vmcnt(0) drain)
//     is what lands it -- so HBM latency hides under compute, and the
//     full-drain cost is paid once per 24-row tile, not once per block.
//   - LDS 2 x 20480 B = 40 KB/block -> 4 blocks/CU = exactly 160 KiB.
//   - Compute mapping identical to the verified v5 kernel.

#define BB 16
#define CC 64
#define HH 192
#define WW 192
#define KERLEN (CC * 9)     // 576 per batch
#define QW (WW / 4)         // 48 quads per row
#define OUTR 24             // output rows per tile (8*24 = 192, no tail tile)
#define NTIL 8              // tiles per plane
#define ROWB (WW * 4)       // 768 bytes per row
#define CHUNKS 5            // 5 x 4096 B staged per window
#define WINB (CHUNKS * 4096)   // 20480 B: rows 0..25 full + partial row 26
#define WINF (WINB / 4)     // 5120 floats

typedef float f4 __attribute__((ext_vector_type(4)));

// ---- Kernel 1: generate the 1024 per-(b,c) 3x3 kernels into d_ws ----
__global__ __launch_bounds__(256) void gen_kernels(
    const float* __restrict__ d,   // (B, C)
    const float* __restrict__ w1,  // (C, C)
    const float* __restrict__ w2,  // (C*9, C)
    float* __restrict__ ker)       // (B*C*9)
{
    __shared__ float dd[CC];
    __shared__ float hid[CC];
    const int b = blockIdx.x;
    const int t = threadIdx.x;

    if (t < CC) dd[t] = d[b * CC + t];
    __syncthreads();

    if (t < CC) {
        const float* w1r = w1 + t * CC;
        float acc = 0.f;
        #pragma unroll 8
        for (int m = 0; m < CC; ++m) acc += dd[m] * w1r[m];
        hid[t] = acc > 0.f ? acc : 0.1f * acc;
    }
    __syncthreads();

    for (int o = t; o < KERLEN; o += 256) {
        const float* w2r = w2 + o * CC;
        float acc = 0.f;
        #pragma unroll 8
        for (int k = 0; k < CC; ++k) acc += hid[k] * w2r[k];
        ker[b * KERLEN + o] = acc;
    }
}

// Stage one 26-row window (global rows wstart..wstart+26, clamped for address
// safety; garbage tail rows are never read) into buf. 5 x 16B per thread,
// all lanes active in every instruction (LDS dest = uniform base + lane*16).
__device__ __forceinline__ void stage_window(const float* __restrict__ xp,
                                             float* __restrict__ buf,
                                             int wstart, int t) {
    #pragma unroll
    for (int i = 0; i < CHUNKS; ++i) {
        const int off = i * 4096 + t * 16;        // byte offset in window
        const int row = off / ROWB;               // staged row 0..26
        const int col = off - row * ROWB;         // byte col, 16B aligned
        int srow = wstart + row;
        srow = srow < 0 ? 0 : (srow > HH - 1 ? HH - 1 : srow);
        __builtin_amdgcn_global_load_lds(
            (const __attribute__((address_space(1))) unsigned int*)
                (xp + srow * WW + (col >> 2)),
            (__attribute__((address_space(3))) unsigned int*)(buf + (off >> 2)),
            16, 0, 0);
    }
}

// ---- Kernel 2: depthwise 3x3, persistent plane block, safe dbuf pipeline ----
__global__ __launch_bounds__(256, 4) void dconv3x3_v7(
    const float* __restrict__ x,    // (B*C, H, W)
    const float* __restrict__ ker,  // (B*C, 9)
    float* __restrict__ out)        // (B*C, H, W)
{
    __shared__ __align__(16) float lds[2][WINF];   // 2 x 20480 B = 40 KB

    const int bc = blockIdx.x;
    const int t  = threadIdx.x;

    const float* __restrict__ xp = x   + (size_t)bc * HH * WW;
    float* __restrict__       op = out + (size_t)bc * HH * WW;

    const float* kp = ker + bc * 9;
    const float k00 = kp[0], k01 = kp[1], k02 = kp[2];
    const float k10 = kp[3], k11 = kp[4], k12 = kp[5];
    const float k20 = kp[6], k21 = kp[7], k22 = kp[8];

    // prologue: stage window 0 (rows -1..25, clamped) and land it
    stage_window(xp, lds[0], -1, t);
    __syncthreads();

    for (int tt = 0; tt < NTIL; ++tt) {
        // issue next window into the other buffer; lands at the syncthreads
        // at the END of this iteration (latency hidden under compute).
        if (tt < NTIL - 1)
            stage_window(xp, lds[(tt + 1) & 1], (tt + 1) * OUTR - 1, t);

        const float* __restrict__ buf = lds[tt & 1];
        const int out0 = tt * OUTR;

        #pragma unroll
        for (int k = 0; k < 5; ++k) {
            const int task = t + k * 256;          // row-major over (row, quad)
            if (task < OUTR * QW) {                // 1152 tasks per tile
                const int rl = task / QW;          // local out row 0..23
                const int q  = task - rl * QW;     // quad col 0..47
                const bool hasL = (q > 0);
                const bool hasR = (q < QW - 1);
                const int  offL = hasL ? -1 : 0;
                const int  offR = hasR ?  4 : 0;
                const int  gr   = out0 + rl;       // global out row

                f4 c[3]; float l[3], r[3];
                const f4 zero = {0.f, 0.f, 0.f, 0.f};
                #pragma unroll
                for (int dj = 0; dj < 3; ++dj) {
                    const int gin = gr - 1 + dj;   // global input row
                    const float* p = buf + (rl + dj) * WW + q * 4;
                    const f4 v     = *(const f4*)p;
                    const float lv = p[offL];
                    const float rv = p[offR];
                    const bool ok  = (unsigned)gin < (unsigned)HH;
                    c[dj] = ok ? v : zero;
                    l[dj] = (ok && hasL) ? lv : 0.f;
                    r[dj] = (ok && hasR) ? rv : 0.f;
                }

                f4 o;
                o.x = k00 * l[0]   + k01 * c[0].x + k02 * c[0].y
                    + k10 * l[1]   + k11 * c[1].x + k12 * c[1].y
                    + k20 * l[2]   + k21 * c[2].x + k22 * c[2].y;
                o.y = k00 * c[0].x + k01 * c[0].y + k02 * c[0].z
                    + k10 * c[1].x + k11 * c[1].y + k12 * c[1].z
                    + k20 * c[2].x + k21 * c[2].y + k22 * c[2].z;
                o.z = k00 * c[0].y + k01 * c[0].z + k02 * c[0].w
                    + k10 * c[1].y + k11 * c[1].z + k12 * c[1].w
                    + k20 * c[2].y + k21 * c[2].z + k22 * c[2].w;
                o.w = k00 * c[0].z + k01 * c[0].w + k02 * r[0]
                    + k10 * c[1].z + k11 * c[1].w + k12 * r[1]
                    + k20 * c[2].z + k21 * c[2].w + k22 * r[2];

                __builtin_nontemporal_store(o, (f4*)(op + (size_t)gr * WW + q * 4));
            }
        }

        // lands next window for ALL waves + protects the buffer being
        // overwritten next iteration (its readers all passed this barrier).
        __syncthreads();
    }
}

extern "C" void kernel_launch(void* const* d_in, const int* in_sizes, int n_in,
                              void* d_out, int out_size, void* d_ws, size_t ws_size,
                              hipStream_t stream) {
    const float* x0 = (const float*)d_in[0];  // (16,64,192,192)
    const float* d  = (const float*)d_in[1];  // (16,64)
    const float* w1 = (const float*)d_in[2];  // (64,64)
    const float* w2 = (const float*)d_in[3];  // (576,64)
    float* out = (float*)d_out;
    float* ker = (float*)d_ws;                // 9216 floats

    gen_kernels<<<BB, 256, 0, stream>>>(d, w1, w2, ker);
    dconv3x3_v7<<<BB * CC, 256, 0, stream>>>(x0, ker, out);
}